// Round 4
// baseline (223.913 us; speedup 1.0000x reference)
//
#include <hip/hip_runtime.h>
#include <math.h>

// B=65536, F=512, K=1299.
// R1-R3: atomics->partials, batched rows (main ~43us). R4/R5/R7: cache hints
// (nt, agent-scope sc1) neutral-to-negative -> can't steer L2 from HIP.
// R6: 2x occupancy neutral -> not latency-bound.
// Standing arithmetic: main 43us == 268MB/6.3TB/s. Ideal = 140MB/6.3 = 22us.
// The extra 134MB is the center gather missing L2 (input stream flushes the
// 4MB/XCD L2) and L3 (harness poisons 536MB between iterations).
// R8: eliminate the gather. Counting-sort rows by label (histogram+scatter,
// ~2us), then one block per label: center row loaded ONCE to registers,
// ~50 input rows streamed (2KB contiguous each -> full coalescing).
// Center traffic 134MB -> 2.66MB. Predict compute ~23us, total ~175us.
// Fallback to R6 path if ws_size too small.
// R9: infra failure on R8 bench (container died twice) -- resubmitted
// unchanged to get the discriminating measurement.

#define F_DIM 512
#define K_CENTERS 1299
#define CAP 256              // max bucket size; binomial mean 50.4, sd 7.1
#define B_ROWS 65536

// fallback-path geometry (R6)
#define ROWS_PER_WAVE 4
#define WAVES_PER_BLOCK 4
#define NUM_BLOCKS 4096

typedef float fx4 __attribute__((ext_vector_type(4)));

// ---------------- R8 bucketed path ----------------

__global__ __launch_bounds__(256) void zero_counts_kernel(int* __restrict__ counts)
{
    const int i = blockIdx.x * 256 + threadIdx.x;
    if (i < K_CENTERS) counts[i] = 0;
}

__global__ __launch_bounds__(256) void bucket_scatter_kernel(
    const int* __restrict__ label,
    int* __restrict__ counts,
    int* __restrict__ buckets)
{
    const int i = blockIdx.x * 256 + threadIdx.x;   // grid 256 -> exactly B_ROWS
    const int lab = label[i];
    const int pos = atomicAdd(&counts[lab], 1);
    if (pos < CAP) buckets[lab * CAP + pos] = i;
}

__global__ __launch_bounds__(256) void bucket_compute_kernel(
    const float* __restrict__ input,    // (B, F) streamed once, coalesced rows
    const float* __restrict__ factor,   // (B,)
    const float* __restrict__ centers,  // (K, F) -- each row read once per block
    const int*   __restrict__ counts,
    const int*   __restrict__ buckets,
    float* __restrict__ out,            // [0]=loss, [1..B]=predict_a
    float* __restrict__ partials)       // (K_CENTERS,)
{
    const int L    = blockIdx.x;
    const int wave = threadIdx.x >> 6;
    const int lane = threadIdx.x & 63;

    const int n = min(counts[L], CAP);

    // center row for this label: 2KB, held in registers per wave
    const fx4* __restrict__ cp = (const fx4*)(centers + (size_t)L * F_DIM);
    const fx4 w0 = cp[lane];
    const fx4 w1 = cp[lane + 64];

    float acc = 0.0f;
    for (int i = wave; i < n; i += WAVES_PER_BLOCK) {
        const int row = __builtin_amdgcn_readfirstlane(buckets[L * CAP + i]);
        const fx4* __restrict__ ip = (const fx4*)(input + (size_t)row * F_DIM);
        const fx4 a0 = ip[lane];
        const fx4 a1 = ip[lane + 64];

        float dot = a0.x * w0.x + a0.y * w0.y + a0.z * w0.z + a0.w * w0.w
                  + a1.x * w1.x + a1.y * w1.y + a1.z * w1.z + a1.w * w1.w;
        #pragma unroll
        for (int off = 32; off > 0; off >>= 1)
            dot += __shfl_xor(dot, off, 64);

        if (lane == 0) {
            const float pa = 12.0f * tanhf(dot);
            out[1 + row] = pa;
            const float d  = pa - factor[row];
            const float ad = fabsf(d);
            acc += (ad < 1.0f) ? 0.5f * d * d : (ad - 0.5f);
        }
    }

    __shared__ float sh[WAVES_PER_BLOCK];
    if (lane == 0) sh[wave] = acc;
    __syncthreads();
    if (threadIdx.x == 0)
        partials[L] = ((sh[0] + sh[1]) + (sh[2] + sh[3])) * (1.0f / 65536.0f);
}

__global__ __launch_bounds__(256) void reduce_bucket_kernel(
    const float* __restrict__ partials, float* __restrict__ out)
{
    __shared__ float sh[4];
    const int wave = threadIdx.x >> 6;
    const int lane = threadIdx.x & 63;

    float s = 0.0f;
    for (int i = threadIdx.x; i < K_CENTERS; i += 256)
        s += partials[i];

    #pragma unroll
    for (int off = 32; off > 0; off >>= 1)
        s += __shfl_xor(s, off, 64);

    if (lane == 0) sh[wave] = s;
    __syncthreads();
    if (threadIdx.x == 0)
        out[0] = (sh[0] + sh[1]) + (sh[2] + sh[3]);
}

// ---------------- R6 fallback path (proven 192us) ----------------

__global__ __launch_bounds__(256) void prediction_loss_kernel(
    const float* __restrict__ input,
    const float* __restrict__ factor,
    const int*   __restrict__ label,
    const float* __restrict__ centers,
    float* __restrict__ out,
    float* __restrict__ partials)
{
    const int wave = threadIdx.x >> 6;
    const int lane = threadIdx.x & 63;
    const int b0 = (blockIdx.x * WAVES_PER_BLOCK + wave) * ROWS_PER_WAVE;

    int c[ROWS_PER_WAVE];
    #pragma unroll
    for (int r = 0; r < ROWS_PER_WAVE; ++r)
        c[r] = __builtin_amdgcn_readfirstlane(label[b0 + r]);

    fx4 a0[ROWS_PER_WAVE], a1[ROWS_PER_WAVE];
    #pragma unroll
    for (int r = 0; r < ROWS_PER_WAVE; ++r) {
        const fx4* __restrict__ ip =
            (const fx4*)(input + (size_t)(b0 + r) * F_DIM);
        a0[r] = __builtin_nontemporal_load(ip + lane);
        a1[r] = __builtin_nontemporal_load(ip + lane + 64);
    }
    fx4 w0[ROWS_PER_WAVE], w1[ROWS_PER_WAVE];
    #pragma unroll
    for (int r = 0; r < ROWS_PER_WAVE; ++r) {
        const fx4* __restrict__ cp =
            (const fx4*)(centers + (size_t)c[r] * F_DIM);
        w0[r] = cp[lane];
        w1[r] = cp[lane + 64];
    }

    float dot[ROWS_PER_WAVE];
    #pragma unroll
    for (int r = 0; r < ROWS_PER_WAVE; ++r) {
        dot[r] = a0[r].x * w0[r].x + a0[r].y * w0[r].y
               + a0[r].z * w0[r].z + a0[r].w * w0[r].w
               + a1[r].x * w1[r].x + a1[r].y * w1[r].y
               + a1[r].z * w1[r].z + a1[r].w * w1[r].w;
    }

    #pragma unroll
    for (int off = 32; off > 0; off >>= 1) {
        #pragma unroll
        for (int r = 0; r < ROWS_PER_WAVE; ++r)
            dot[r] += __shfl_xor(dot[r], off, 64);
    }

    const int sel = lane & 3;
    float v = dot[0];
    #pragma unroll
    for (int r = 1; r < ROWS_PER_WAVE; ++r)
        v = (sel == r) ? dot[r] : v;

    const float pa = 12.0f * tanhf(v);

    float contrib = 0.0f;
    if (lane < ROWS_PER_WAVE) {
        out[1 + b0 + lane] = pa;
        const float d  = pa - factor[b0 + lane];
        const float ad = fabsf(d);
        contrib = (ad < 1.0f) ? 0.5f * d * d : (ad - 0.5f);
    }
    contrib += __shfl_xor(contrib, 2, 64);
    contrib += __shfl_xor(contrib, 1, 64);

    __shared__ float sh[WAVES_PER_BLOCK];
    if (lane == 0) sh[wave] = contrib;
    __syncthreads();
    if (threadIdx.x == 0)
        partials[blockIdx.x] =
            ((sh[0] + sh[1]) + (sh[2] + sh[3])) * (1.0f / 65536.0f);
}

__global__ __launch_bounds__(256) void reduce_partials_kernel(
    const float* __restrict__ partials, float* __restrict__ out)
{
    __shared__ float sh[4];
    const int wave = threadIdx.x >> 6;
    const int lane = threadIdx.x & 63;

    float s = 0.0f;
    #pragma unroll
    for (int i = 0; i < NUM_BLOCKS / 256; ++i)
        s += partials[threadIdx.x + i * 256];

    #pragma unroll
    for (int off = 32; off > 0; off >>= 1)
        s += __shfl_xor(s, off, 64);

    if (lane == 0) sh[wave] = s;
    __syncthreads();
    if (threadIdx.x == 0)
        out[0] = (sh[0] + sh[1]) + (sh[2] + sh[3]);
}

// ---------------- launch ----------------

extern "C" void kernel_launch(void* const* d_in, const int* in_sizes, int n_in,
                              void* d_out, int out_size, void* d_ws, size_t ws_size,
                              hipStream_t stream) {
    const float* input   = (const float*)d_in[0];
    const float* factor  = (const float*)d_in[1];
    const int*   label   = (const int*)d_in[2];
    const float* centers = (const float*)d_in[3];
    float* out = (float*)d_out;

    char* ws = (char*)d_ws;
    int*   counts   = (int*)ws;                                    // 1299 ints
    int*   buckets  = (int*)(ws + 8192);                           // 1299*CAP ints
    float* bpartial = (float*)(ws + 8192 + (size_t)K_CENTERS * CAP * 4);
    const size_t needed = 8192 + (size_t)K_CENTERS * CAP * 4 + K_CENTERS * 4;

    if (ws_size >= needed) {
        zero_counts_kernel<<<(K_CENTERS + 255) / 256, 256, 0, stream>>>(counts);
        bucket_scatter_kernel<<<B_ROWS / 256, 256, 0, stream>>>(label, counts, buckets);
        bucket_compute_kernel<<<K_CENTERS, 256, 0, stream>>>(
            input, factor, centers, counts, buckets, out, bpartial);
        reduce_bucket_kernel<<<1, 256, 0, stream>>>(bpartial, out);
    } else {
        float* partials = (float*)d_ws;   // NUM_BLOCKS floats
        prediction_loss_kernel<<<NUM_BLOCKS, 256, 0, stream>>>(
            input, factor, label, centers, out, partials);
        reduce_partials_kernel<<<1, 256, 0, stream>>>(partials, out);
    }
}

// Round 5
// 219.765 us; speedup vs baseline: 1.0189x; 1.0189x over previous
//
#include <hip/hip_runtime.h>
#include <math.h>

// B=65536, F=512, K=1299.
// R1-R3: atomics->partials, batched rows (main ~43us). R4/R5/R7: cache hints
// neutral-to-negative. R6: 2x occupancy neutral -> not latency-bound (in the
// streaming kernel). Standing arithmetic: main 43us == 268MB/6.3TB/s; the
// extra 134MB is the center gather missing thrashed L2 + poisoned L3.
// R8: bucketed (one block per label, center-once) REGRESSED 192->224us.
// Post-mortem: R8 compute did 1 row/wave/iter -> serial chain
// (bucket idx load -> input load -> reduce), only 2 loads in flight vs 16
// in R6. Latency failure, not a traffic-theory refutation.
// R10 (this): bucketed path + R6-style batching. 4 rows/wave/iter via one
// int4 index load, 8 input loads in flight, batched 4-chain butterfly,
// sel-trick epilogue. Center row loaded once per block into regs.
// Predict bucket_compute ~25us @ ~140MB, total ~178us.
// If ~192: random 2KB-row DRAM efficiency = gather cost -> revert+declare.

#define F_DIM 512
#define K_CENTERS 1299
#define CAP 256              // max bucket size; binomial mean 50.4, sd 7.1
#define B_ROWS 65536

// fallback-path geometry (R6)
#define ROWS_PER_WAVE 4
#define WAVES_PER_BLOCK 4
#define NUM_BLOCKS 4096

typedef float fx4 __attribute__((ext_vector_type(4)));

// ---------------- R10 bucketed path ----------------

__global__ __launch_bounds__(256) void zero_counts_kernel(int* __restrict__ counts)
{
    const int i = blockIdx.x * 256 + threadIdx.x;
    if (i < K_CENTERS) counts[i] = 0;
}

__global__ __launch_bounds__(256) void bucket_scatter_kernel(
    const int* __restrict__ label,
    int* __restrict__ counts,
    int* __restrict__ buckets)
{
    const int i = blockIdx.x * 256 + threadIdx.x;   // grid 256 -> exactly B_ROWS
    const int lab = label[i];
    const int pos = atomicAdd(&counts[lab], 1);
    if (pos < CAP) buckets[lab * CAP + pos] = i;
}

__global__ __launch_bounds__(256) void bucket_compute_kernel(
    const float* __restrict__ input,    // (B, F) read once, 2KB rows coalesced
    const float* __restrict__ factor,   // (B,)
    const float* __restrict__ centers,  // (K, F) -- each row read once per block
    const int*   __restrict__ counts,
    const int*   __restrict__ buckets,
    float* __restrict__ out,            // [0]=loss, [1..B]=predict_a
    float* __restrict__ partials)       // (K_CENTERS,)
{
    const int L    = blockIdx.x;
    const int wave = threadIdx.x >> 6;
    const int lane = threadIdx.x & 63;

    const int n = min(counts[L], CAP);

    // center row for this label: 2KB, held in registers (same for all waves)
    const fx4* __restrict__ cp = (const fx4*)(centers + (size_t)L * F_DIM);
    const fx4 w0 = cp[lane];
    const fx4 w1 = cp[lane + 64];

    const int4* __restrict__ bp = (const int4*)(buckets + (size_t)L * CAP);

    float acc = 0.0f;
    // each wave takes 4 consecutive rows per iteration; 16 rows/block/iter
    for (int base = wave * 4; base < n; base += 4 * WAVES_PER_BLOCK) {
        const int4 ri = bp[base >> 2];          // one 16B index load
        const int rr[4] = { __builtin_amdgcn_readfirstlane(ri.x),
                            __builtin_amdgcn_readfirstlane(ri.y),
                            __builtin_amdgcn_readfirstlane(ri.z),
                            __builtin_amdgcn_readfirstlane(ri.w) };

        // 8 input loads in flight (wave-uniform validity -> no divergence)
        fx4 a0[4], a1[4];
        #pragma unroll
        for (int r = 0; r < 4; ++r) {
            if (base + r < n) {
                const fx4* __restrict__ ip =
                    (const fx4*)(input + (size_t)rr[r] * F_DIM);
                a0[r] = ip[lane];
                a1[r] = ip[lane + 64];
            } else {
                a0[r] = (fx4){0.f, 0.f, 0.f, 0.f};
                a1[r] = (fx4){0.f, 0.f, 0.f, 0.f};
            }
        }

        float dot[4];
        #pragma unroll
        for (int r = 0; r < 4; ++r) {
            dot[r] = a0[r].x * w0.x + a0[r].y * w0.y
                   + a0[r].z * w0.z + a0[r].w * w0.w
                   + a1[r].x * w1.x + a1[r].y * w1.y
                   + a1[r].z * w1.z + a1[r].w * w1.w;
        }

        // batched butterfly: 6 steps x 4 independent chains
        #pragma unroll
        for (int off = 32; off > 0; off >>= 1) {
            #pragma unroll
            for (int r = 0; r < 4; ++r)
                dot[r] += __shfl_xor(dot[r], off, 64);
        }

        // sel trick: lane r (r<4) handles row rr[r]; compile-time indices only
        const int sel = lane & 3;
        float v = dot[0];
        int   rowSel = rr[0];
        #pragma unroll
        for (int r = 1; r < 4; ++r) {
            v      = (sel == r) ? dot[r] : v;
            rowSel = (sel == r) ? rr[r]  : rowSel;
        }

        if (lane < 4 && base + lane < n) {
            const float pa = 12.0f * tanhf(v);
            out[1 + rowSel] = pa;
            const float d  = pa - factor[rowSel];
            const float ad = fabsf(d);
            acc += (ad < 1.0f) ? 0.5f * d * d : (ad - 0.5f);
        }
    }

    // sum lanes 0..3 within the wave
    acc += __shfl_xor(acc, 2, 64);
    acc += __shfl_xor(acc, 1, 64);

    __shared__ float sh[WAVES_PER_BLOCK];
    if (lane == 0) sh[wave] = acc;
    __syncthreads();
    if (threadIdx.x == 0)
        partials[L] = ((sh[0] + sh[1]) + (sh[2] + sh[3])) * (1.0f / 65536.0f);
}

__global__ __launch_bounds__(256) void reduce_bucket_kernel(
    const float* __restrict__ partials, float* __restrict__ out)
{
    __shared__ float sh[4];
    const int wave = threadIdx.x >> 6;
    const int lane = threadIdx.x & 63;

    float s = 0.0f;
    for (int i = threadIdx.x; i < K_CENTERS; i += 256)
        s += partials[i];

    #pragma unroll
    for (int off = 32; off > 0; off >>= 1)
        s += __shfl_xor(s, off, 64);

    if (lane == 0) sh[wave] = s;
    __syncthreads();
    if (threadIdx.x == 0)
        out[0] = (sh[0] + sh[1]) + (sh[2] + sh[3]);
}

// ---------------- R6 fallback path (proven 192us) ----------------

__global__ __launch_bounds__(256) void prediction_loss_kernel(
    const float* __restrict__ input,
    const float* __restrict__ factor,
    const int*   __restrict__ label,
    const float* __restrict__ centers,
    float* __restrict__ out,
    float* __restrict__ partials)
{
    const int wave = threadIdx.x >> 6;
    const int lane = threadIdx.x & 63;
    const int b0 = (blockIdx.x * WAVES_PER_BLOCK + wave) * ROWS_PER_WAVE;

    int c[ROWS_PER_WAVE];
    #pragma unroll
    for (int r = 0; r < ROWS_PER_WAVE; ++r)
        c[r] = __builtin_amdgcn_readfirstlane(label[b0 + r]);

    fx4 a0[ROWS_PER_WAVE], a1[ROWS_PER_WAVE];
    #pragma unroll
    for (int r = 0; r < ROWS_PER_WAVE; ++r) {
        const fx4* __restrict__ ip =
            (const fx4*)(input + (size_t)(b0 + r) * F_DIM);
        a0[r] = __builtin_nontemporal_load(ip + lane);
        a1[r] = __builtin_nontemporal_load(ip + lane + 64);
    }
    fx4 w0[ROWS_PER_WAVE], w1[ROWS_PER_WAVE];
    #pragma unroll
    for (int r = 0; r < ROWS_PER_WAVE; ++r) {
        const fx4* __restrict__ cp =
            (const fx4*)(centers + (size_t)c[r] * F_DIM);
        w0[r] = cp[lane];
        w1[r] = cp[lane + 64];
    }

    float dot[ROWS_PER_WAVE];
    #pragma unroll
    for (int r = 0; r < ROWS_PER_WAVE; ++r) {
        dot[r] = a0[r].x * w0[r].x + a0[r].y * w0[r].y
               + a0[r].z * w0[r].z + a0[r].w * w0[r].w
               + a1[r].x * w1[r].x + a1[r].y * w1[r].y
               + a1[r].z * w1[r].z + a1[r].w * w1[r].w;
    }

    #pragma unroll
    for (int off = 32; off > 0; off >>= 1) {
        #pragma unroll
        for (int r = 0; r < ROWS_PER_WAVE; ++r)
            dot[r] += __shfl_xor(dot[r], off, 64);
    }

    const int sel = lane & 3;
    float v = dot[0];
    #pragma unroll
    for (int r = 1; r < ROWS_PER_WAVE; ++r)
        v = (sel == r) ? dot[r] : v;

    const float pa = 12.0f * tanhf(v);

    float contrib = 0.0f;
    if (lane < ROWS_PER_WAVE) {
        out[1 + b0 + lane] = pa;
        const float d  = pa - factor[b0 + lane];
        const float ad = fabsf(d);
        contrib = (ad < 1.0f) ? 0.5f * d * d : (ad - 0.5f);
    }
    contrib += __shfl_xor(contrib, 2, 64);
    contrib += __shfl_xor(contrib, 1, 64);

    __shared__ float sh[WAVES_PER_BLOCK];
    if (lane == 0) sh[wave] = contrib;
    __syncthreads();
    if (threadIdx.x == 0)
        partials[blockIdx.x] =
            ((sh[0] + sh[1]) + (sh[2] + sh[3])) * (1.0f / 65536.0f);
}

__global__ __launch_bounds__(256) void reduce_partials_kernel(
    const float* __restrict__ partials, float* __restrict__ out)
{
    __shared__ float sh[4];
    const int wave = threadIdx.x >> 6;
    const int lane = threadIdx.x & 63;

    float s = 0.0f;
    #pragma unroll
    for (int i = 0; i < NUM_BLOCKS / 256; ++i)
        s += partials[threadIdx.x + i * 256];

    #pragma unroll
    for (int off = 32; off > 0; off >>= 1)
        s += __shfl_xor(s, off, 64);

    if (lane == 0) sh[wave] = s;
    __syncthreads();
    if (threadIdx.x == 0)
        out[0] = (sh[0] + sh[1]) + (sh[2] + sh[3]);
}

// ---------------- launch ----------------

extern "C" void kernel_launch(void* const* d_in, const int* in_sizes, int n_in,
                              void* d_out, int out_size, void* d_ws, size_t ws_size,
                              hipStream_t stream) {
    const float* input   = (const float*)d_in[0];
    const float* factor  = (const float*)d_in[1];
    const int*   label   = (const int*)d_in[2];
    const float* centers = (const float*)d_in[3];
    float* out = (float*)d_out;

    char* ws = (char*)d_ws;
    int*   counts   = (int*)ws;                                    // 1299 ints
    int*   buckets  = (int*)(ws + 8192);                           // 1299*CAP ints
    float* bpartial = (float*)(ws + 8192 + (size_t)K_CENTERS * CAP * 4);
    const size_t needed = 8192 + (size_t)K_CENTERS * CAP * 4 + K_CENTERS * 4;

    if (ws_size >= needed) {
        zero_counts_kernel<<<(K_CENTERS + 255) / 256, 256, 0, stream>>>(counts);
        bucket_scatter_kernel<<<B_ROWS / 256, 256, 0, stream>>>(label, counts, buckets);
        bucket_compute_kernel<<<K_CENTERS, 256, 0, stream>>>(
            input, factor, centers, counts, buckets, out, bpartial);
        reduce_bucket_kernel<<<1, 256, 0, stream>>>(bpartial, out);
    } else {
        float* partials = (float*)d_ws;   // NUM_BLOCKS floats
        prediction_loss_kernel<<<NUM_BLOCKS, 256, 0, stream>>>(
            input, factor, label, centers, out, partials);
        reduce_partials_kernel<<<1, 256, 0, stream>>>(partials, out);
    }
}